// Round 6
// baseline (171.726 us; speedup 1.0000x reference)
//
#include <hip/hip_runtime.h>
#include <cmath>

namespace {

constexpr int N = 32, T = 1024, C = 512, K = 64;
constexpr float EPS = 1e-12f;
constexpr int SR = 40;        // shorts per LDS row: 32 data + 8 pad (80 B, 16B-aligned)
constexpr int PL = 64 * SR;   // plane size in shorts (2560)

typedef short s8v __attribute__((ext_vector_type(8)));   // 8 x bf16 bits
typedef short s4v __attribute__((ext_vector_type(4)));   // 4 x bf16 bits
typedef float f4v __attribute__((ext_vector_type(4)));   // MFMA accumulator

__device__ inline unsigned short f2bh(float f) {
  __bf16 h = (__bf16)f;
  return __builtin_bit_cast(unsigned short, h);
}
__device__ inline float bh2f(unsigned short u) {
  __bf16 h = __builtin_bit_cast(__bf16, u);
  return (float)h;
}
__device__ inline void cvt4(const float4 v, s4v& h, s4v& l) {
  const float e[4] = {v.x, v.y, v.z, v.w};
#pragma unroll
  for (int i = 0; i < 4; ++i) {
    unsigned short hb = f2bh(e[i]);
    h[i] = (short)hb;
    l[i] = (short)f2bh(e[i] - bh2f(hb));
  }
}

#define MFMA16(A, B, Cc) __builtin_amdgcn_mfma_f32_16x16x32_bf16((A), (B), (Cc), 0, 0, 0)

// ---------------------------------------------------------------------------
// k_gemm1: logits = x @ W^T + b (split-bf16 3-pass MFMA), softmax over K,
// writes a^T [n][k][t] fp32 + asum_part[block][64].
// Grid NT/64 = 512 x 256 threads (4 waves; wave = 32t x 32k, 2x2 micro).
// Double-buffered BK=32 pipeline: one barrier per tile; global loads for
// tile i+1 in flight during MFMA on tile i; convert+store after MFMA.
// ---------------------------------------------------------------------------
__global__ __launch_bounds__(256, 2) void k_gemm1(
    const float* __restrict__ x, const float* __restrict__ W,
    const float* __restrict__ b, float* __restrict__ aT,
    float* __restrict__ asum_part) {
  __shared__ __align__(16) unsigned short sm[2][4 * PL];  // 40960 B
  __shared__ float asum_l[256];

  const int tid = threadIdx.x;
  const int w = tid >> 6, lane = tid & 63, lm = lane & 15, lq = lane >> 4;
  const int th = w >> 1;  // t-half (32 rows)
  const int kh = w & 1;   // k-half (32 cols)
  const long r0 = (long)blockIdx.x * 64;
  const int n = blockIdx.x >> 4, tl = blockIdx.x & 15;

  f4v acc[2][2] = {};
  float4 px[2], pw[2];

  // preload tile 0
#pragma unroll
  for (int r = 0; r < 2; ++r) {
    const int u = tid + r * 256, t = u >> 3, cg = u & 7;
    px[r] = *(const float4*)&x[(r0 + t) * C + cg * 4];
    pw[r] = *(const float4*)&W[(long)t * C + cg * 4];
  }
  // stage tile 0 -> buf 0
  {
    unsigned short* xh = sm[0];
    unsigned short* xl = sm[0] + PL;
    unsigned short* wh = sm[0] + 2 * PL;
    unsigned short* wl = sm[0] + 3 * PL;
#pragma unroll
    for (int r = 0; r < 2; ++r) {
      const int u = tid + r * 256, t = u >> 3, cg = u & 7;
      s4v h, l;
      cvt4(px[r], h, l);
      *(s4v*)&xh[t * SR + cg * 4] = h;
      *(s4v*)&xl[t * SR + cg * 4] = l;
      cvt4(pw[r], h, l);
      *(s4v*)&wh[t * SR + cg * 4] = h;
      *(s4v*)&wl[t * SR + cg * 4] = l;
    }
  }
  __syncthreads();

  for (int it = 0; it < 16; ++it) {
    const int cur = it & 1;
    if (it < 15) {  // issue global loads for tile it+1 (fly during MFMA)
      const int c0 = (it + 1) * 32;
#pragma unroll
      for (int r = 0; r < 2; ++r) {
        const int u = tid + r * 256, t = u >> 3, cg = u & 7;
        px[r] = *(const float4*)&x[(r0 + t) * C + c0 + cg * 4];
        pw[r] = *(const float4*)&W[(long)t * C + c0 + cg * 4];
      }
    }
    {  // compute from buf[cur]
      const unsigned short* xh = sm[cur];
      const unsigned short* xl = sm[cur] + PL;
      const unsigned short* wh = sm[cur] + 2 * PL;
      const unsigned short* wl = sm[cur] + 3 * PL;
      s8v ah[2], al[2], bh[2], bl[2];
#pragma unroll
      for (int i = 0; i < 2; ++i) {
        ah[i] = *(const s8v*)&xh[(th * 32 + i * 16 + lm) * SR + lq * 8];
        al[i] = *(const s8v*)&xl[(th * 32 + i * 16 + lm) * SR + lq * 8];
        bh[i] = *(const s8v*)&wh[(kh * 32 + i * 16 + lm) * SR + lq * 8];
        bl[i] = *(const s8v*)&wl[(kh * 32 + i * 16 + lm) * SR + lq * 8];
      }
#pragma unroll
      for (int i = 0; i < 2; ++i)
#pragma unroll
        for (int j = 0; j < 2; ++j) {
          acc[i][j] = MFMA16(ah[i], bh[j], acc[i][j]);
          acc[i][j] = MFMA16(ah[i], bl[j], acc[i][j]);
          acc[i][j] = MFMA16(al[i], bh[j], acc[i][j]);
        }
    }
    if (it < 15) {  // convert + stage tile it+1 -> other buffer
      unsigned short* xh = sm[cur ^ 1];
      unsigned short* xl = sm[cur ^ 1] + PL;
      unsigned short* wh = sm[cur ^ 1] + 2 * PL;
      unsigned short* wl = sm[cur ^ 1] + 3 * PL;
#pragma unroll
      for (int r = 0; r < 2; ++r) {
        const int u = tid + r * 256, t = u >> 3, cg = u & 7;
        s4v h, l;
        cvt4(px[r], h, l);
        *(s4v*)&xh[t * SR + cg * 4] = h;
        *(s4v*)&xl[t * SR + cg * 4] = l;
        cvt4(pw[r], h, l);
        *(s4v*)&wh[t * SR + cg * 4] = h;
        *(s4v*)&wl[t * SR + cg * 4] = l;
      }
    }
    __syncthreads();
  }

  // logits + bias -> LDS Ls[64 t][68] fp32 ; Ls2 = a^T staging [64 k][68]
  float* Ls = (float*)&sm[0][0];   // 17408 B (fits in 20480)
  float* Ls2 = (float*)&sm[1][0];  // 17408 B
  const float bias[2] = {b[kh * 32 + lm], b[kh * 32 + 16 + lm]};
#pragma unroll
  for (int i = 0; i < 2; ++i)
#pragma unroll
    for (int j = 0; j < 2; ++j)
#pragma unroll
      for (int r = 0; r < 4; ++r)
        Ls[(th * 32 + i * 16 + lq * 4 + r) * 68 + kh * 32 + j * 16 + lm] =
            acc[i][j][r] + bias[j];
  __syncthreads();

  // softmax: 4 threads per t-row, 16 k each, register + shfl
  {
    const int row = tid >> 2, q = tid & 3;
    float av[16];
#pragma unroll
    for (int u = 0; u < 4; ++u)
      *(float4*)&av[u * 4] = *(const float4*)&Ls[row * 68 + q * 16 + u * 4];
    float m = av[0];
#pragma unroll
    for (int i = 1; i < 16; ++i) m = fmaxf(m, av[i]);
    m = fmaxf(m, __shfl_xor(m, 1, 64));
    m = fmaxf(m, __shfl_xor(m, 2, 64));
    float sum = 0.f;
#pragma unroll
    for (int i = 0; i < 16; ++i) {
      av[i] = __expf(av[i] - m);
      sum += av[i];
    }
    sum += __shfl_xor(sum, 1, 64);
    sum += __shfl_xor(sum, 2, 64);
    const float inv = 1.f / sum;
    float ps[16];
#pragma unroll
    for (int i = 0; i < 16; ++i) {
      av[i] *= inv;
      ps[i] = av[i];
      Ls2[(q * 16 + i) * 68 + row] = av[i];  // transposed a^T [k][t]
    }
#pragma unroll
    for (int s = 4; s < 64; s <<= 1)
#pragma unroll
      for (int i = 0; i < 16; ++i) ps[i] += __shfl_xor(ps[i], s, 64);
    if (lane < 4) {
#pragma unroll
      for (int i = 0; i < 16; ++i) asum_l[w * 64 + q * 16 + i] = ps[i];
    }
  }
  __syncthreads();

  if (tid < 64) {
    asum_part[(n * 16 + tl) * 64 + tid] = asum_l[tid] + asum_l[64 + tid] +
                                          asum_l[128 + tid] + asum_l[192 + tid];
  }
#pragma unroll
  for (int r = 0; r < 4; ++r) {
    const int u = tid + r * 256, k = u >> 4, tg = u & 15;
    *(float4*)&aT[((long)n * K + k) * T + tl * 64 + tg * 4] =
        *(const float4*)&Ls2[k * 68 + tg * 4];
  }
}

// ---------------------------------------------------------------------------
// k_gemm2: vlad[n,k,c] = sum_t a[t,k]*x[t,c] - asum*cent, full T per block.
// Grid N*8 = 256 blocks (n, 64c) x 256 threads (4 waves; wave = 32k x 32c).
// Double-buffered BK=32 pipeline; staging split: waves 0-1 transpose x,
// waves 2-3 convert aT. Fused epilogue (centroid subtract, sumsq partials).
// ---------------------------------------------------------------------------
__global__ __launch_bounds__(256, 2) void k_gemm2(
    const float* __restrict__ x, const float* __restrict__ aT,
    const float* __restrict__ asum_part, const float* __restrict__ cent,
    float* __restrict__ vlad, float* __restrict__ ssq_part) {
  __shared__ __align__(16) unsigned short sm[2][4 * PL];  // 40960 B
  __shared__ float asum_l[64];
  __shared__ float ssq_l[128];

  const int tid = threadIdx.x;
  const int w = tid >> 6, lane = tid & 63, lm = lane & 15, lq = lane >> 4;
  const int kh = w >> 1;  // 32k half
  const int ch = w & 1;   // 32c half
  const int n = blockIdx.x >> 3, cb = blockIdx.x & 7;
  const int c0 = cb * 64;

  if (tid < 64) {
    float s = 0.f;
#pragma unroll
    for (int tl = 0; tl < 16; ++tl) s += asum_part[(n * 16 + tl) * 64 + tid];
    asum_l[tid] = s;
  }

  const bool xrole = (tid < 128);          // waves 0-1: x ; waves 2-3: aT
  const int xcg = tid & 15, xtq = (tid >> 4) & 7;
  const int au = tid & 127, ak = au >> 1, atg = au & 1;

  f4v acc[2][2] = {};
  float4 p[4];

  // preload tile 0
  if (xrole) {
#pragma unroll
    for (int i = 0; i < 4; ++i)
      p[i] = *(const float4*)&x[((long)n * T + xtq * 4 + i) * C + c0 + xcg * 4];
  } else {
#pragma unroll
    for (int q = 0; q < 4; ++q)
      p[q] = *(const float4*)&aT[((long)n * K + ak) * T + atg * 16 + q * 4];
  }
  // stage tile 0 -> buf 0
  {
    unsigned short* ah = sm[0];
    unsigned short* al = sm[0] + PL;
    unsigned short* xh = sm[0] + 2 * PL;
    unsigned short* xl = sm[0] + 3 * PL;
    if (xrole) {
#pragma unroll
      for (int cc = 0; cc < 4; ++cc) {
        s4v h, l;
#pragma unroll
        for (int i = 0; i < 4; ++i) {
          const float e = ((const float*)&p[i])[cc];
          unsigned short hb = f2bh(e);
          h[i] = (short)hb;
          l[i] = (short)f2bh(e - bh2f(hb));
        }
        *(s4v*)&xh[(xcg * 4 + cc) * SR + xtq * 4] = h;
        *(s4v*)&xl[(xcg * 4 + cc) * SR + xtq * 4] = l;
      }
    } else {
#pragma unroll
      for (int q = 0; q < 4; ++q) {
        s4v h, l;
        cvt4(p[q], h, l);
        *(s4v*)&ah[ak * SR + atg * 16 + q * 4] = h;
        *(s4v*)&al[ak * SR + atg * 16 + q * 4] = l;
      }
    }
  }
  __syncthreads();

  for (int it = 0; it < 32; ++it) {
    const int cur = it & 1;
    if (it < 31) {  // issue global loads for tile it+1
      const int t0 = (it + 1) * 32;
      if (xrole) {
#pragma unroll
        for (int i = 0; i < 4; ++i)
          p[i] = *(const float4*)&x[((long)n * T + t0 + xtq * 4 + i) * C + c0 +
                                    xcg * 4];
      } else {
#pragma unroll
        for (int q = 0; q < 4; ++q)
          p[q] =
              *(const float4*)&aT[((long)n * K + ak) * T + t0 + atg * 16 + q * 4];
      }
    }
    {  // compute from buf[cur]
      const unsigned short* ahp = sm[cur];
      const unsigned short* alp = sm[cur] + PL;
      const unsigned short* xhp = sm[cur] + 2 * PL;
      const unsigned short* xlp = sm[cur] + 3 * PL;
      s8v ah[2], al[2], bh[2], bl[2];
#pragma unroll
      for (int i = 0; i < 2; ++i) {
        ah[i] = *(const s8v*)&ahp[(kh * 32 + i * 16 + lm) * SR + lq * 8];
        al[i] = *(const s8v*)&alp[(kh * 32 + i * 16 + lm) * SR + lq * 8];
        bh[i] = *(const s8v*)&xhp[(ch * 32 + i * 16 + lm) * SR + lq * 8];
        bl[i] = *(const s8v*)&xlp[(ch * 32 + i * 16 + lm) * SR + lq * 8];
      }
#pragma unroll
      for (int i = 0; i < 2; ++i)
#pragma unroll
        for (int j = 0; j < 2; ++j) {
          acc[i][j] = MFMA16(ah[i], bh[j], acc[i][j]);
          acc[i][j] = MFMA16(ah[i], bl[j], acc[i][j]);
          acc[i][j] = MFMA16(al[i], bh[j], acc[i][j]);
        }
    }
    if (it < 31) {  // convert + stage tile it+1 -> other buffer
      unsigned short* ah = sm[cur ^ 1];
      unsigned short* al = sm[cur ^ 1] + PL;
      unsigned short* xh = sm[cur ^ 1] + 2 * PL;
      unsigned short* xl = sm[cur ^ 1] + 3 * PL;
      if (xrole) {
#pragma unroll
        for (int cc = 0; cc < 4; ++cc) {
          s4v h, l;
#pragma unroll
          for (int i = 0; i < 4; ++i) {
            const float e = ((const float*)&p[i])[cc];
            unsigned short hb = f2bh(e);
            h[i] = (short)hb;
            l[i] = (short)f2bh(e - bh2f(hb));
          }
          *(s4v*)&xh[(xcg * 4 + cc) * SR + xtq * 4] = h;
          *(s4v*)&xl[(xcg * 4 + cc) * SR + xtq * 4] = l;
        }
      } else {
#pragma unroll
        for (int q = 0; q < 4; ++q) {
          s4v h, l;
          cvt4(p[q], h, l);
          *(s4v*)&ah[ak * SR + atg * 16 + q * 4] = h;
          *(s4v*)&al[ak * SR + atg * 16 + q * 4] = l;
        }
      }
    }
    __syncthreads();
  }

  // fused epilogue: subtract asum*cent, write vlad, sumsq partials
  float ssq[2][4];
#pragma unroll
  for (int i = 0; i < 2; ++i)
#pragma unroll
    for (int r = 0; r < 4; ++r) ssq[i][r] = 0.f;

#pragma unroll
  for (int i = 0; i < 2; ++i) {
#pragma unroll
    for (int r = 0; r < 4; ++r) {
      const int k = kh * 32 + i * 16 + lq * 4 + r;
      const float as = asum_l[k];
#pragma unroll
      for (int j = 0; j < 2; ++j) {
        const int c = c0 + ch * 32 + j * 16 + lm;
        const float v = acc[i][j][r] - as * cent[(long)k * C + c];
        vlad[((long)n * K + k) * C + c] = v;
        ssq[i][r] += v * v;
      }
    }
  }
#pragma unroll
  for (int i = 0; i < 2; ++i)
#pragma unroll
    for (int r = 0; r < 4; ++r) {
      float s = ssq[i][r];
      s += __shfl_xor(s, 1, 64);
      s += __shfl_xor(s, 2, 64);
      s += __shfl_xor(s, 4, 64);
      s += __shfl_xor(s, 8, 64);
      ssq[i][r] = s;
    }
  if (lm == 0) {
#pragma unroll
    for (int i = 0; i < 2; ++i)
#pragma unroll
      for (int r = 0; r < 4; ++r)
        ssq_l[(kh * 32 + i * 16 + lq * 4 + r) * 2 + ch] = ssq[i][r];
  }
  __syncthreads();
  if (tid < 64)
    ssq_part[(n * 8 + cb) * 64 + tid] = ssq_l[tid * 2] + ssq_l[tid * 2 + 1];
}

// ---------------------------------------------------------------------------
// k_norm: out = vlad / (||vlad_k|| * ||intra-normed||). Grid N*16 x 256.
// ---------------------------------------------------------------------------
__global__ __launch_bounds__(256) void k_norm(
    const float* __restrict__ vlad, const float* __restrict__ ssq_part,
    float* __restrict__ out) {
  __shared__ float denom[64];
  __shared__ float contrib[64];
  __shared__ float ginv;

  const int tid = threadIdx.x;
  const int n = blockIdx.x >> 4;
  const int chunk = blockIdx.x & 15;

  if (tid < 64) {
    float ss = 0.f;
#pragma unroll
    for (int cb = 0; cb < 8; ++cb) ss += ssq_part[(n * 8 + cb) * 64 + tid];
    const float d = fmaxf(sqrtf(ss), EPS);
    denom[tid] = d;
    contrib[tid] = ss / (d * d);
  }
  __syncthreads();
  if (tid == 0) {
    float s = 0.f;
#pragma unroll
    for (int k = 0; k < K; ++k) s += contrib[k];
    ginv = 1.0f / fmaxf(sqrtf(s), EPS);
  }
  __syncthreads();

#pragma unroll
  for (int q = 0; q < 2; ++q) {
    const int f4 = tid + q * 256;
    const long off = chunk * 2048 + (long)f4 * 4;
    const int k = (int)(off >> 9);
    float4 v = *(const float4*)&vlad[(long)n * K * C + off];
    const float sc = ginv / denom[k];
    v.x *= sc; v.y *= sc; v.z *= sc; v.w *= sc;
    *(float4*)&out[(long)n * K * C + off] = v;
  }
}

}  // namespace

extern "C" void kernel_launch(void* const* d_in, const int* in_sizes, int n_in,
                              void* d_out, int out_size, void* d_ws,
                              size_t ws_size, hipStream_t stream) {
  const float* x = reinterpret_cast<const float*>(d_in[0]);     // [N,T,C]
  const float* W = reinterpret_cast<const float*>(d_in[1]);     // [K,C]
  const float* b = reinterpret_cast<const float*>(d_in[2]);     // [K]
  const float* cent = reinterpret_cast<const float*>(d_in[3]);  // [K,C]
  float* out = reinterpret_cast<float*>(d_out);                 // [N, K*C]

  float* p = reinterpret_cast<float*>(d_ws);
  float* aTg = p;                 p += (size_t)N * K * T;  // 8 MiB
  float* vlad = p;                p += (size_t)N * K * C;  // 4 MiB
  float* asum_part = p;           p += (size_t)512 * 64;   // 128 KiB
  float* ssq_part = p;            // 64 KiB

  k_gemm1<<<(N * T) / 64, 256, 0, stream>>>(x, W, b, aTg, asum_part);
  k_gemm2<<<N * 8, 256, 0, stream>>>(x, aTg, asum_part, cent, vlad, ssq_part);
  k_norm<<<N * 16, 256, 0, stream>>>(vlad, ssq_part, out);
}

// Round 7
// 132.873 us; speedup vs baseline: 1.2924x; 1.2924x over previous
//
#include <hip/hip_runtime.h>
#include <cmath>

namespace {

constexpr int N = 32, T = 1024, C = 512, K = 64;
constexpr float EPS = 1e-12f;

typedef short s8v __attribute__((ext_vector_type(8)));   // 8 x bf16 bits
typedef short s4v __attribute__((ext_vector_type(4)));   // 4 x bf16 bits
typedef float f4v __attribute__((ext_vector_type(4)));   // MFMA accumulator

__device__ inline unsigned short f2bh(float f) {
  __bf16 h = (__bf16)f;
  return __builtin_bit_cast(unsigned short, h);
}
__device__ inline float bh2f(unsigned short u) {
  __bf16 h = __builtin_bit_cast(__bf16, u);
  return (float)h;
}

#define MFMA16(A, B, Cc) __builtin_amdgcn_mfma_f32_16x16x32_bf16((A), (B), (Cc), 0, 0, 0)

// ---------------------------------------------------------------------------
// k_gemm1: logits = x @ W^T + b (split-bf16 3-pass MFMA), softmax over K,
// writes a^T [n][k][t] fp32 + asum_part[block][64].
// Grid NT/64 = 512 x 256 threads (4 waves; wave = 32t x 32k, 2x2 micro).
// BK=64, two barriers per tile, register prefetch of next c-chunk.
// ---------------------------------------------------------------------------
__global__ __launch_bounds__(256, 4) void k_gemm1(
    const float* __restrict__ x, const float* __restrict__ W,
    const float* __restrict__ b, float* __restrict__ aT,
    float* __restrict__ asum_part) {
  __shared__ __align__(16) unsigned short sm[4 * 64 * 72];  // 36864 B
  __shared__ float asum_l[256];
  unsigned short* xh_s = sm;                // [64 t][72] bf16
  unsigned short* xl_s = sm + 64 * 72;
  unsigned short* wh_s = sm + 2 * 64 * 72;  // [64 k][72]
  unsigned short* wl_s = sm + 3 * 64 * 72;

  const int tid = threadIdx.x;
  const int w = tid >> 6, lane = tid & 63, lm = lane & 15, lq = lane >> 4;
  const int th = w >> 1;  // t-half (32 rows)
  const int kh = w & 1;   // k-half (32 cols)
  const long r0 = (long)blockIdx.x * 64;
  const int n = blockIdx.x >> 4, tl = blockIdx.x & 15;

  f4v acc[2][2] = {};
  float4 px[4], pw[4];
#pragma unroll
  for (int r = 0; r < 4; ++r) {
    const int f = tid + r * 256, t = f >> 4, cg = f & 15;
    px[r] = *(const float4*)&x[(r0 + t) * C + cg * 4];
    pw[r] = *(const float4*)&W[(long)t * C + cg * 4];
  }

  for (int c0 = 0; c0 < C; c0 += 64) {
    __syncthreads();
#pragma unroll
    for (int r = 0; r < 4; ++r) {
      const int f = tid + r * 256, t = f >> 4, cg = f & 15;
      const float ex[4] = {px[r].x, px[r].y, px[r].z, px[r].w};
      const float ew[4] = {pw[r].x, pw[r].y, pw[r].z, pw[r].w};
      s4v xh, xl, wh, wl;
#pragma unroll
      for (int i = 0; i < 4; ++i) {
        unsigned short hb = f2bh(ex[i]);
        xh[i] = (short)hb; xl[i] = (short)f2bh(ex[i] - bh2f(hb));
        hb = f2bh(ew[i]);
        wh[i] = (short)hb; wl[i] = (short)f2bh(ew[i] - bh2f(hb));
      }
      *(s4v*)&xh_s[t * 72 + cg * 4] = xh;
      *(s4v*)&xl_s[t * 72 + cg * 4] = xl;
      *(s4v*)&wh_s[t * 72 + cg * 4] = wh;
      *(s4v*)&wl_s[t * 72 + cg * 4] = wl;
    }
    if (c0 + 64 < C) {  // prefetch next chunk
#pragma unroll
      for (int r = 0; r < 4; ++r) {
        const int f = tid + r * 256, t = f >> 4, cg = f & 15;
        px[r] = *(const float4*)&x[(r0 + t) * C + c0 + 64 + cg * 4];
        pw[r] = *(const float4*)&W[(long)t * C + c0 + 64 + cg * 4];
      }
    }
    __syncthreads();

#pragma unroll
    for (int ks = 0; ks < 2; ++ks) {
      const int col = ks * 32 + lq * 8;
      s8v ah[2], al[2], bh[2], bl[2];
#pragma unroll
      for (int i = 0; i < 2; ++i) {
        ah[i] = *(const s8v*)&xh_s[(th * 32 + i * 16 + lm) * 72 + col];
        al[i] = *(const s8v*)&xl_s[(th * 32 + i * 16 + lm) * 72 + col];
        bh[i] = *(const s8v*)&wh_s[(kh * 32 + i * 16 + lm) * 72 + col];
        bl[i] = *(const s8v*)&wl_s[(kh * 32 + i * 16 + lm) * 72 + col];
      }
#pragma unroll
      for (int i = 0; i < 2; ++i)
#pragma unroll
        for (int j = 0; j < 2; ++j) {
          acc[i][j] = MFMA16(ah[i], bh[j], acc[i][j]);
          acc[i][j] = MFMA16(ah[i], bl[j], acc[i][j]);
          acc[i][j] = MFMA16(al[i], bh[j], acc[i][j]);
        }
    }
  }
  __syncthreads();

  // logits + bias -> LDS Ls[64 t][68] fp32 ; Ls2 = a^T staging [64 k][68]
  float* Ls = (float*)sm;            // 17408 B
  float* Ls2 = (float*)(sm + 8704);  // 17408 B
  const float bias[2] = {b[kh * 32 + lm], b[kh * 32 + 16 + lm]};
#pragma unroll
  for (int i = 0; i < 2; ++i)
#pragma unroll
    for (int j = 0; j < 2; ++j)
#pragma unroll
      for (int r = 0; r < 4; ++r)
        Ls[(th * 32 + i * 16 + lq * 4 + r) * 68 + kh * 32 + j * 16 + lm] =
            acc[i][j][r] + bias[j];
  __syncthreads();

  // softmax: 4 threads per t-row, 16 k each, register + shfl
  {
    const int row = tid >> 2, q = tid & 3;
    float av[16];
#pragma unroll
    for (int u = 0; u < 4; ++u)
      *(float4*)&av[u * 4] = *(const float4*)&Ls[row * 68 + q * 16 + u * 4];
    float m = av[0];
#pragma unroll
    for (int i = 1; i < 16; ++i) m = fmaxf(m, av[i]);
    m = fmaxf(m, __shfl_xor(m, 1, 64));
    m = fmaxf(m, __shfl_xor(m, 2, 64));
    float sum = 0.f;
#pragma unroll
    for (int i = 0; i < 16; ++i) {
      av[i] = __expf(av[i] - m);
      sum += av[i];
    }
    sum += __shfl_xor(sum, 1, 64);
    sum += __shfl_xor(sum, 2, 64);
    const float inv = 1.f / sum;
    float ps[16];
#pragma unroll
    for (int i = 0; i < 16; ++i) {
      av[i] *= inv;
      ps[i] = av[i];
      Ls2[(q * 16 + i) * 68 + row] = av[i];  // transposed a^T [k][t]
    }
#pragma unroll
    for (int s = 4; s < 64; s <<= 1)
#pragma unroll
      for (int i = 0; i < 16; ++i) ps[i] += __shfl_xor(ps[i], s, 64);
    if (lane < 4) {
#pragma unroll
      for (int i = 0; i < 16; ++i) asum_l[w * 64 + q * 16 + i] = ps[i];
    }
  }
  __syncthreads();

  if (tid < 64) {
    asum_part[(n * 16 + tl) * 64 + tid] = asum_l[tid] + asum_l[64 + tid] +
                                          asum_l[128 + tid] + asum_l[192 + tid];
  }
#pragma unroll
  for (int r = 0; r < 4; ++r) {
    const int u = tid + r * 256, k = u >> 4, tg = u & 15;
    *(float4*)&aT[((long)n * K + k) * T + tl * 64 + tg * 4] =
        *(const float4*)&Ls2[k * 68 + tg * 4];
  }
}

// ---------------------------------------------------------------------------
// k_gemm2: part[tc][n][k][c] = sum_{t in half} a[t,k]*x[t,c].
// Grid N*16 = 512 blocks (n, tc, 64c) x 256 threads -> 2 blocks/CU.
// BK=64 two-barrier structure with register prefetch (round-5 proven shape).
// ---------------------------------------------------------------------------
__global__ __launch_bounds__(256, 2) void k_gemm2(
    const float* __restrict__ x, const float* __restrict__ aT,
    float* __restrict__ part) {
  __shared__ __align__(16) unsigned short sm[4 * 64 * 72];  // 36864 B
  unsigned short* ah_s = sm;                // a^T hi [64 k][72]
  unsigned short* al_s = sm + 64 * 72;
  unsigned short* xh_s = sm + 2 * 64 * 72;  // x^T hi [64 c][72]
  unsigned short* xl_s = sm + 3 * 64 * 72;

  const int tid = threadIdx.x;
  const int w = tid >> 6, lane = tid & 63, lm = lane & 15, lq = lane >> 4;
  const int kh = w >> 1;  // 32k half
  const int ch = w & 1;   // 32c half
  const int n = blockIdx.x >> 4;
  const int tc = (blockIdx.x >> 3) & 1;
  const int cb = blockIdx.x & 7;
  const int c0 = cb * 64;
  const int tbase = tc * (T / 2);

  f4v acc[2][2] = {};
  float4 pa[4], px[4];
#pragma unroll
  for (int r = 0; r < 4; ++r) {
    const int u = tid + r * 256, k = u >> 4, tg = u & 15;
    pa[r] = *(const float4*)&aT[((long)n * K + k) * T + tbase + tg * 4];
  }
  {
    const int cg = tid & 15, tq = tid >> 4;
#pragma unroll
    for (int i = 0; i < 4; ++i)
      px[i] = *(const float4*)&x[((long)n * T + tbase + tq * 4 + i) * C + c0 +
                                 cg * 4];
  }

  for (int t0 = tbase; t0 < tbase + T / 2; t0 += 64) {
    __syncthreads();
    // a^T: fp32 -> hi/lo
#pragma unroll
    for (int r = 0; r < 4; ++r) {
      const int u = tid + r * 256, k = u >> 4, tg = u & 15;
      const float e[4] = {pa[r].x, pa[r].y, pa[r].z, pa[r].w};
      s4v h, l;
#pragma unroll
      for (int i = 0; i < 4; ++i) {
        unsigned short hb = f2bh(e[i]);
        h[i] = (short)hb;
        l[i] = (short)f2bh(e[i] - bh2f(hb));
      }
      *(s4v*)&ah_s[k * 72 + tg * 4] = h;
      *(s4v*)&al_s[k * 72 + tg * 4] = l;
    }
    // x^T: fp32 -> hi/lo, 4-t packed transposed writes
    {
      const int cg = tid & 15, tq = tid >> 4, t4 = tq * 4;
      float e[4][4];
#pragma unroll
      for (int i = 0; i < 4; ++i) {
        e[i][0] = px[i].x; e[i][1] = px[i].y;
        e[i][2] = px[i].z; e[i][3] = px[i].w;
      }
#pragma unroll
      for (int cc = 0; cc < 4; ++cc) {
        s4v h, l;
#pragma unroll
        for (int i = 0; i < 4; ++i) {
          unsigned short hb = f2bh(e[i][cc]);
          h[i] = (short)hb;
          l[i] = (short)f2bh(e[i][cc] - bh2f(hb));
        }
        *(s4v*)&xh_s[(cg * 4 + cc) * 72 + t4] = h;
        *(s4v*)&xl_s[(cg * 4 + cc) * 72 + t4] = l;
      }
    }
    if (t0 + 64 < tbase + T / 2) {  // prefetch next t-tile
#pragma unroll
      for (int r = 0; r < 4; ++r) {
        const int u = tid + r * 256, k = u >> 4, tg = u & 15;
        pa[r] = *(const float4*)&aT[((long)n * K + k) * T + t0 + 64 + tg * 4];
      }
      const int cg = tid & 15, tq = tid >> 4;
#pragma unroll
      for (int i = 0; i < 4; ++i)
        px[i] = *(const float4*)&x[((long)n * T + t0 + 64 + tq * 4 + i) * C +
                                   c0 + cg * 4];
    }
    __syncthreads();

#pragma unroll
    for (int ks = 0; ks < 2; ++ks) {
      const int col = ks * 32 + lq * 8;
      s8v ah[2], al[2], bh[2], bl[2];
#pragma unroll
      for (int i = 0; i < 2; ++i) {
        ah[i] = *(const s8v*)&ah_s[(kh * 32 + i * 16 + lm) * 72 + col];
        al[i] = *(const s8v*)&al_s[(kh * 32 + i * 16 + lm) * 72 + col];
        bh[i] = *(const s8v*)&xh_s[(ch * 32 + i * 16 + lm) * 72 + col];
        bl[i] = *(const s8v*)&xl_s[(ch * 32 + i * 16 + lm) * 72 + col];
      }
#pragma unroll
      for (int i = 0; i < 2; ++i)
#pragma unroll
        for (int j = 0; j < 2; ++j) {
          acc[i][j] = MFMA16(ah[i], bh[j], acc[i][j]);
          acc[i][j] = MFMA16(ah[i], bl[j], acc[i][j]);
          acc[i][j] = MFMA16(al[i], bh[j], acc[i][j]);
        }
    }
  }

  float* pb = part + ((long)tc * N + n) * K * C;
#pragma unroll
  for (int i = 0; i < 2; ++i)
#pragma unroll
    for (int j = 0; j < 2; ++j)
#pragma unroll
      for (int r = 0; r < 4; ++r) {
        const int k = kh * 32 + i * 16 + lq * 4 + r;
        const int c = c0 + ch * 32 + j * 16 + lm;
        pb[(long)k * C + c] = acc[i][j][r];
      }
}

// ---------------------------------------------------------------------------
// k_stat: vlad = part0 + part1 - asum*cent ; ssq[n][k].
// Grid N*8 = 256 blocks (n, 8-k chunk) x 256 threads, 16 elems/thread.
// ---------------------------------------------------------------------------
__global__ __launch_bounds__(256) void k_stat(
    const float* __restrict__ part, const float* __restrict__ asum_part,
    const float* __restrict__ cent, float* __restrict__ vlad,
    float* __restrict__ ssq) {
  __shared__ float asum_l[8];
  __shared__ float ssq_l[8];
  const int tid = threadIdx.x;
  const int n = blockIdx.x >> 3;
  const int kc = blockIdx.x & 7;  // 8 k per block

  if (tid < 8) {
    float s = 0.f;
#pragma unroll
    for (int tl = 0; tl < 16; ++tl)
      s += asum_part[(n * 16 + tl) * 64 + kc * 8 + tid];
    asum_l[tid] = s;
  }
  __syncthreads();

  const int kl = tid >> 5;  // local k (32 threads per k)
  const float as = asum_l[kl];
  const long Lb = (long)kc * 4096 + tid * 16;        // linear within [K*C]
  const long nb = (long)n * K * C;

  float ss = 0.f;
#pragma unroll
  for (int q = 0; q < 4; ++q) {
    const float4 p0 = *(const float4*)&part[nb + Lb + q * 4];
    const float4 p1 = *(const float4*)&part[(long)N * K * C + nb + Lb + q * 4];
    const float4 cv = *(const float4*)&cent[Lb + q * 4];
    float4 v;
    v.x = p0.x + p1.x - as * cv.x;
    v.y = p0.y + p1.y - as * cv.y;
    v.z = p0.z + p1.z - as * cv.z;
    v.w = p0.w + p1.w - as * cv.w;
    *(float4*)&vlad[nb + Lb + q * 4] = v;
    ss += v.x * v.x + v.y * v.y + v.z * v.z + v.w * v.w;
  }
#pragma unroll
  for (int s = 1; s < 32; s <<= 1) ss += __shfl_xor(ss, s, 64);
  if ((tid & 31) == 0) ssq_l[kl] = ss;
  __syncthreads();
  if (tid < 8) ssq[n * K + kc * 8 + tid] = ssq_l[tid];
}

// ---------------------------------------------------------------------------
// k_norm: out = vlad / (||vlad_k|| * ||intra-normed||). Grid N*16 x 256.
// ---------------------------------------------------------------------------
__global__ __launch_bounds__(256) void k_norm(
    const float* __restrict__ vlad, const float* __restrict__ ssq,
    float* __restrict__ out) {
  __shared__ float denom[64];
  __shared__ float contrib[64];
  __shared__ float ginv;

  const int tid = threadIdx.x;
  const int n = blockIdx.x >> 4;
  const int chunk = blockIdx.x & 15;

  if (tid < 64) {
    const float sv = ssq[n * K + tid];
    const float d = fmaxf(sqrtf(sv), EPS);
    denom[tid] = d;
    contrib[tid] = sv / (d * d);
  }
  __syncthreads();
  if (tid == 0) {
    float s = 0.f;
#pragma unroll
    for (int k = 0; k < K; ++k) s += contrib[k];
    ginv = 1.0f / fmaxf(sqrtf(s), EPS);
  }
  __syncthreads();

#pragma unroll
  for (int q = 0; q < 2; ++q) {
    const int f4 = tid + q * 256;
    const long off = chunk * 2048 + (long)f4 * 4;
    const int k = (int)(off >> 9);
    float4 v = *(const float4*)&vlad[(long)n * K * C + off];
    const float sc = ginv / denom[k];
    v.x *= sc; v.y *= sc; v.z *= sc; v.w *= sc;
    *(float4*)&out[(long)n * K * C + off] = v;
  }
}

}  // namespace

extern "C" void kernel_launch(void* const* d_in, const int* in_sizes, int n_in,
                              void* d_out, int out_size, void* d_ws,
                              size_t ws_size, hipStream_t stream) {
  const float* x = reinterpret_cast<const float*>(d_in[0]);     // [N,T,C]
  const float* W = reinterpret_cast<const float*>(d_in[1]);     // [K,C]
  const float* b = reinterpret_cast<const float*>(d_in[2]);     // [K]
  const float* cent = reinterpret_cast<const float*>(d_in[3]);  // [K,C]
  float* out = reinterpret_cast<float*>(d_out);                 // [N, K*C]

  float* p = reinterpret_cast<float*>(d_ws);
  float* aTg = p;                 p += (size_t)N * K * T;      // 8 MiB
  float* part = p;                p += (size_t)2 * N * K * C;  // 8 MiB
  float* asum_part = p;           p += (size_t)512 * 64;       // 128 KiB
  float* ssq = p;                 p += (size_t)N * K;          // 8 KiB
  float* vlad = aTg;  // aliases a^T (dead after k_gemm2)

  k_gemm1<<<(N * T) / 64, 256, 0, stream>>>(x, W, b, aTg, asum_part);
  k_gemm2<<<N * 16, 256, 0, stream>>>(x, aTg, part);
  k_stat<<<N * 8, 256, 0, stream>>>(part, asum_part, cent, vlad, ssq);
  k_norm<<<N * 16, 256, 0, stream>>>(vlad, ssq, out);
}